// Round 8
// baseline (36.661 us; speedup 1.0000x reference)
//
#include <hip/hip_runtime.h>

#define NROWS 2048
#define MCOLS 2048
#define DDIM  64
#define TI    128   // k1 tile rows
#define TJ    64    // k1 tile cols
#define NTI1  (NROWS / TI)   // 16 k1 tile-rows
#define NTJ   (MCOLS / TJ)   // 32 tile-cols
#define TILE2 64             // k2 tile
#define NTI2  (NROWS / TILE2) // 32 k2 tile-rows

// clang-native 4-float vector: accepted by __builtin_nontemporal_{load,store}
typedef float f32x4 __attribute__((ext_vector_type(4)));

// ============================================================================
// K1: 128x64 tile, 8x4 per thread. Computes s tile (register-resident),
// stores s (non-temporal) + per-tile (max, expsum) partials for rows & cols.
//   rm_part/rs_part: [NTJ][NROWS]   cm_part/cs_part: [NTI1][MCOLS]
// ============================================================================
__global__ __launch_bounds__(256) void k1_dist(
    const float* __restrict__ zx, const float* __restrict__ zy,
    float* __restrict__ s_out,
    float* __restrict__ rm_part, float* __restrict__ rs_part,
    float* __restrict__ cm_part, float* __restrict__ cs_part)
{
  __shared__ float sX[DDIM][TI];   // [d][i]  32 KB
  __shared__ float sY[DDIM][TJ];   // [d][j]  16 KB
  __shared__ float cmw[4][TJ];
  __shared__ float csw[4][TJ];

  const int bi = blockIdx.y, bj = blockIdx.x;
  const int t  = threadIdx.x;
  const int lid = t & 63, wv = t >> 6;
  const int i0 = (t >> 4) << 3;   // 0..120, 8 rows per thread
  const int j0 = (t & 15) << 2;   // 0..60,  4 cols per thread

  // ---- stage zx rows (128 rows x 64 d): 2 threads/row, 32 d each ----
  {
    int r = t & 127, half = t >> 7;
    const float* zxp = zx + (size_t)(bi * TI + r) * DDIM + half * 32;
#pragma unroll
    for (int q = 0; q < 8; ++q) {
      float4 v = *(const float4*)(zxp + q * 4);
      int d = half * 32 + q * 4;
      sX[d+0][r]=v.x; sX[d+1][r]=v.y; sX[d+2][r]=v.z; sX[d+3][r]=v.w;
    }
  }
  // ---- stage zy rows (64 rows x 64 d): 4 threads/row, 16 d each ----
  {
    int r = t & 63, quad = t >> 6;
    const float* zyp = zy + (size_t)(bj * TJ + r) * DDIM + quad * 16;
#pragma unroll
    for (int q = 0; q < 4; ++q) {
      float4 v = *(const float4*)(zyp + q * 4);
      int d = quad * 16 + q * 4;
      sY[d+0][r]=v.x; sY[d+1][r]=v.y; sY[d+2][r]=v.z; sY[d+3][r]=v.w;
    }
  }
  __syncthreads();

  // ---- distances: acc[8][4] ----
  float acc[8][4] = {{0.f}};
#pragma unroll 4
  for (int d = 0; d < DDIM; ++d) {
    float4 x0 = *(const float4*)&sX[d][i0];
    float4 x1 = *(const float4*)&sX[d][i0 + 4];
    float4 yv = *(const float4*)&sY[d][j0];
    float xr[8] = {x0.x, x0.y, x0.z, x0.w, x1.x, x1.y, x1.z, x1.w};
    float yc[4] = {yv.x, yv.y, yv.z, yv.w};
#pragma unroll
    for (int a = 0; a < 8; ++a)
#pragma unroll
      for (int b = 0; b < 4; ++b)
        acc[a][b] += fabsf(xr[a] - yc[b]);
  }
  float sv[8][4];
#pragma unroll
  for (int a = 0; a < 8; ++a)
#pragma unroll
    for (int b = 0; b < 4; ++b)
      sv[a][b] = -acc[a][b];

  // ---- store s (non-temporal: written once, read once in k2) ----
#pragma unroll
  for (int a = 0; a < 8; ++a) {
    f32x4 v = { sv[a][0], sv[a][1], sv[a][2], sv[a][3] };
    __builtin_nontemporal_store(v,
        (f32x4*)(s_out + (size_t)(bi * TI + i0 + a) * MCOLS + bj * TJ + j0));
  }

  // ---- row stats: 16 j-lanes (bits 0..3) cover one tile-row ----
  {
    float rm[8], es[8];
#pragma unroll
    for (int a = 0; a < 8; ++a)
      rm[a] = fmaxf(fmaxf(sv[a][0], sv[a][1]), fmaxf(sv[a][2], sv[a][3]));
#pragma unroll
    for (int off = 1; off <= 8; off <<= 1)
#pragma unroll
      for (int a = 0; a < 8; ++a)
        rm[a] = fmaxf(rm[a], __shfl_xor(rm[a], off));
#pragma unroll
    for (int a = 0; a < 8; ++a)
      es[a] = __expf(sv[a][0]-rm[a]) + __expf(sv[a][1]-rm[a])
            + __expf(sv[a][2]-rm[a]) + __expf(sv[a][3]-rm[a]);
#pragma unroll
    for (int off = 1; off <= 8; off <<= 1)
#pragma unroll
      for (int a = 0; a < 8; ++a)
        es[a] += __shfl_xor(es[a], off);
    if ((lid & 15) == 0) {
#pragma unroll
      for (int a = 0; a < 8; ++a) {
        int idx = bj * NROWS + bi * TI + i0 + a;
        rm_part[idx] = rm[a];
        rs_part[idx] = es[a];
      }
    }
  }

  // ---- col stats: lane bits 4..5 (4 i-groups/wave), then LDS across waves --
  {
    float cm[4], ce[4];
#pragma unroll
    for (int b = 0; b < 4; ++b) {
      float m = sv[0][b];
#pragma unroll
      for (int a = 1; a < 8; ++a) m = fmaxf(m, sv[a][b]);
      cm[b] = m;
    }
#pragma unroll
    for (int off = 16; off <= 32; off <<= 1)
#pragma unroll
      for (int b = 0; b < 4; ++b)
        cm[b] = fmaxf(cm[b], __shfl_xor(cm[b], off));
#pragma unroll
    for (int b = 0; b < 4; ++b) {
      float s = 0.f;
#pragma unroll
      for (int a = 0; a < 8; ++a) s += __expf(sv[a][b] - cm[b]);
      ce[b] = s;
    }
#pragma unroll
    for (int off = 16; off <= 32; off <<= 1)
#pragma unroll
      for (int b = 0; b < 4; ++b)
        ce[b] += __shfl_xor(ce[b], off);
    if (lid < 16) {
#pragma unroll
      for (int b = 0; b < 4; ++b) {
        cmw[wv][lid * 4 + b] = cm[b];
        csw[wv][lid * 4 + b] = ce[b];
      }
    }
    __syncthreads();
    if (t < TJ) {
      int j = t;
      float M = fmaxf(fmaxf(cmw[0][j], cmw[1][j]), fmaxf(cmw[2][j], cmw[3][j]));
      float S = __expf(cmw[0][j]-M)*csw[0][j] + __expf(cmw[1][j]-M)*csw[1][j]
              + __expf(cmw[2][j]-M)*csw[2][j] + __expf(cmw[3][j]-M)*csw[3][j];
      int idx = bi * MCOLS + bj * TJ + j;
      cm_part[idx] = M;
      cs_part[idx] = S;
    }
  }
}

// ============================================================================
// K2: per-block redundant stats-reduce + reload s tile (nt) + combine.
// 64x64 tiles, 4x4 per thread. No atomics.
// ============================================================================
__global__ __launch_bounds__(256) void k2_combine(
    const float* __restrict__ s_in,
    const float* __restrict__ rm_part, const float* __restrict__ rs_part,
    const float* __restrict__ cm_part, const float* __restrict__ cs_part,
    float* __restrict__ part /* [NTI2*NTJ][2] */)
{
  __shared__ float l_rmax[TILE2], l_rinv[TILE2];
  __shared__ float l_cmax[TILE2], l_cinv[TILE2];
  __shared__ float red[8];

  int bi = blockIdx.y, bj = blockIdx.x;
  int t  = threadIdx.x;
  int lid = t & 63, wv = t >> 6;
  int i0 = (t >> 4) << 2, j0 = (t & 15) << 2;

  if (t < 64) {
    int i = bi * TILE2 + t;
    float m[NTJ];
#pragma unroll
    for (int tj = 0; tj < NTJ; ++tj) m[tj] = rm_part[tj * NROWS + i];
    float M = m[0];
#pragma unroll
    for (int tj = 1; tj < NTJ; ++tj) M = fmaxf(M, m[tj]);
    float S = 0.f;
#pragma unroll
    for (int tj = 0; tj < NTJ; ++tj)
      S += __expf(m[tj] - M) * rs_part[tj * NROWS + i];
    l_rmax[t] = M;
    l_rinv[t] = 1.f / S;
  } else if (t < 128) {
    int c = t - 64;
    int j = bj * TILE2 + c;
    float m[NTI1];
#pragma unroll
    for (int ti = 0; ti < NTI1; ++ti) m[ti] = cm_part[ti * MCOLS + j];
    float M = m[0];
#pragma unroll
    for (int ti = 1; ti < NTI1; ++ti) M = fmaxf(M, m[ti]);
    float S = 0.f;
#pragma unroll
    for (int ti = 0; ti < NTI1; ++ti)
      S += __expf(m[ti] - M) * cs_part[ti * MCOLS + j];
    l_cmax[c] = M;
    l_cinv[c] = 1.f / S;
  }
  __syncthreads();

  float sv[4][4];
  {
    const float* base = s_in + (size_t)(bi * TILE2 + i0) * MCOLS + bj * TILE2 + j0;
#pragma unroll
    for (int a = 0; a < 4; ++a) {
      f32x4 v = __builtin_nontemporal_load(
          (const f32x4*)(base + (size_t)a * MCOLS));
      sv[a][0] = v.x; sv[a][1] = v.y; sv[a][2] = v.z; sv[a][3] = v.w;
    }
  }
  float rm[4], rv[4], cm[4], cv[4];
#pragma unroll
  for (int a = 0; a < 4; ++a) {
    rm[a] = l_rmax[i0 + a];
    rv[a] = l_rinv[i0 + a];
  }
#pragma unroll
  for (int b = 0; b < 4; ++b) {
    cm[b] = l_cmax[j0 + b];
    cv[b] = l_cinv[j0 + b];
  }
  float pn = 0.f, pd = 0.f;
#pragma unroll
  for (int a = 0; a < 4; ++a)
#pragma unroll
    for (int b = 0; b < 4; ++b) {
      float av = __expf(sv[a][b] - rm[a]) * rv[a];
      float bv = __expf(sv[a][b] - cm[b]) * cv[b];
      float w  = av + bv - av * bv;
      pn += w * sv[a][b];
      pd += w;
    }
#pragma unroll
  for (int off = 1; off <= 32; off <<= 1) {
    pn += __shfl_xor(pn, off);
    pd += __shfl_xor(pd, off);
  }
  if (lid == 0) { red[wv * 2] = pn; red[wv * 2 + 1] = pd; }
  __syncthreads();
  if (t == 0) {
    int bid = bi * NTJ + bj;
    part[bid * 2 + 0] = red[0] + red[2] + red[4] + red[6];
    part[bid * 2 + 1] = red[1] + red[3] + red[5] + red[7];
  }
}

// ============================================================================
// K3: deterministic reduce of 1024 (pn,pd) pairs -> out scalar.
// ============================================================================
__global__ __launch_bounds__(256) void k3_out(
    const float* __restrict__ part, float* __restrict__ out)
{
  int t = threadIdx.x;
  float pn = 0.f, pd = 0.f;
#pragma unroll
  for (int k = t; k < NTI2 * NTJ; k += 256) {
    float2 v = *(const float2*)(part + k * 2);
    pn += v.x;
    pd += v.y;
  }
#pragma unroll
  for (int off = 1; off <= 32; off <<= 1) {
    pn += __shfl_xor(pn, off);
    pd += __shfl_xor(pd, off);
  }
  __shared__ float red[8];
  if ((t & 63) == 0) { red[(t >> 6) * 2] = pn; red[(t >> 6) * 2 + 1] = pd; }
  __syncthreads();
  if (t == 0) {
    float n = red[0] + red[2] + red[4] + red[6];
    float d = red[1] + red[3] + red[5] + red[7];
    out[0] = n / d;
  }
}

extern "C" void kernel_launch(void* const* d_in, const int* in_sizes, int n_in,
                              void* d_out, int out_size, void* d_ws, size_t ws_size,
                              hipStream_t stream)
{
  const float* zx = (const float*)d_in[0];
  const float* zy = (const float*)d_in[1];
  float* out = (float*)d_out;

  char* ws = (char*)d_ws;
  float* part    = (float*)(ws + 0);            // 1024*2 f32 = 8 KB
  float* rm_part = (float*)(ws + (64  << 10));  // [32][2048] f32 = 256 KB
  float* rs_part = (float*)(ws + (320 << 10));
  float* cm_part = (float*)(ws + (576 << 10));  // [16][2048] used
  float* cs_part = (float*)(ws + (832 << 10));
  float* s_buf   = (float*)(ws + (1088 << 10)); // 16 MiB

  k1_dist   <<<dim3(NTJ, NTI1), dim3(256), 0, stream>>>(zx, zy, s_buf,
                rm_part, rs_part, cm_part, cs_part);
  k2_combine<<<dim3(NTJ, NTI2), dim3(256), 0, stream>>>(s_buf,
                rm_part, rs_part, cm_part, cs_part, part);
  k3_out    <<<dim3(1), dim3(256), 0, stream>>>(part, out);
}